// Round 1
// 940.409 us; speedup vs baseline: 1.5217x; 1.5217x over previous
//
#include <hip/hip_runtime.h>

// Problem constants (B,C,H,W = 32,512,32,32)
#define B_N   32
#define C_N   512
#define HW_N  1024
#define C8_N  64
#define MQKV  640   // 64 (q) + 64 (k) + 512 (v) rows

typedef short bf16x8 __attribute__((ext_vector_type(8)));
typedef float f32x4  __attribute__((ext_vector_type(4)));

// round-to-nearest-even fp32 -> bf16, two at a time, packed into one u32
static __device__ __forceinline__ unsigned int pack2_bf16(float a, float b)
{
    unsigned int ua = __float_as_uint(a);
    unsigned int ub = __float_as_uint(b);
    ua = (ua + 0x7fffu + ((ua >> 16) & 1u)) >> 16;
    ub = (ub + 0x7fffu + ((ub >> 16) & 1u)) & 0xffff0000u;
    return ua | ub;
}

// ---------------------------------------------------------------------------
// Kernel 1: fused QKV projection (unchanged).
// ---------------------------------------------------------------------------
__global__ __launch_bounds__(256) void qkv_proj_kernel(
    const float* __restrict__ x,
    const float* __restrict__ wq, const float* __restrict__ bq,
    const float* __restrict__ wk, const float* __restrict__ bk,
    const float* __restrict__ wv, const float* __restrict__ bv,
    float* __restrict__ qkv)
{
    const int b   = blockIdx.z;
    const int m0  = blockIdx.y * 64;    // output row tile (0..639)
    const int p0  = blockIdx.x * 64;    // pixel tile
    const int tid = threadIdx.x;
    const int tx  = tid & 15;           // micro col group
    const int ty  = tid >> 4;           // micro row group

    const float* wmat; const float* bvec; int mb;
    if (m0 < 64)       { wmat = wq; bvec = bq; mb = m0;       }
    else if (m0 < 128) { wmat = wk; bvec = bk; mb = m0 - 64;  }
    else               { wmat = wv; bvec = bv; mb = m0 - 128; }

    __shared__ float Ws[16][65];   // [c][m]  (+1 pad)
    __shared__ float Xs[16][65];   // [c][p]

    float acc[4][4] = {};
    const float* xb = x + (size_t)b * C_N * HW_N;

    for (int c0 = 0; c0 < C_N; c0 += 16) {
        {   // X tile: 16c x 64p, float4 along p
            const int c = tid >> 4;
            const int p = (tid & 15) * 4;
            const float4 t = *(const float4*)(xb + (size_t)(c0 + c) * HW_N + p0 + p);
            Xs[c][p + 0] = t.x; Xs[c][p + 1] = t.y;
            Xs[c][p + 2] = t.z; Xs[c][p + 3] = t.w;
        }
        {   // W tile: 64m x 16c, float4 along c, stored transposed [c][m]
            const int m = tid >> 2;
            const int c = (tid & 3) * 4;
            const float4 t = *(const float4*)(wmat + (size_t)(mb + m) * C_N + c0 + c);
            Ws[c + 0][m] = t.x; Ws[c + 1][m] = t.y;
            Ws[c + 2][m] = t.z; Ws[c + 3][m] = t.w;
        }
        __syncthreads();
        #pragma unroll
        for (int cc = 0; cc < 16; ++cc) {
            float am[4], bp[4];
            #pragma unroll
            for (int i = 0; i < 4; ++i) am[i] = Ws[cc][ty * 4 + i];
            #pragma unroll
            for (int j = 0; j < 4; ++j) bp[j] = Xs[cc][tx * 4 + j];
            #pragma unroll
            for (int i = 0; i < 4; ++i)
                #pragma unroll
                for (int j = 0; j < 4; ++j)
                    acc[i][j] = fmaf(am[i], bp[j], acc[i][j]);
        }
        __syncthreads();
    }

    #pragma unroll
    for (int i = 0; i < 4; ++i) {
        const int gm   = m0 + ty * 4 + i;
        const float bi = bvec[mb + ty * 4 + i];
        float4 r;
        r.x = acc[i][0] + bi; r.y = acc[i][1] + bi;
        r.z = acc[i][2] + bi; r.w = acc[i][3] + bi;
        *(float4*)(qkv + ((size_t)b * MQKV + gm) * HW_N + p0 + tx * 4) = r;
    }
}

// ---------------------------------------------------------------------------
// Kernel 2: energy[b,i,j] = sum_c q[b,c,i] * k[b,c,j]  (unchanged, fp32 exact)
// ---------------------------------------------------------------------------
__global__ __launch_bounds__(256) void energy_kernel(
    const float* __restrict__ qkv, float* __restrict__ att)
{
    const int b   = blockIdx.z;
    const int i0  = blockIdx.y * 64;
    const int j0  = blockIdx.x * 64;
    const int tid = threadIdx.x;
    const int tx  = tid & 15;
    const int ty  = tid >> 4;

    const float* q = qkv + (size_t)b * MQKV * HW_N;   // [64][1024]
    const float* k = q + (size_t)C8_N * HW_N;         // [64][1024]

    __shared__ float Qs[16][65];   // [c][i]
    __shared__ float Ks[16][65];   // [c][j]
    float acc[4][4] = {};

    for (int c0 = 0; c0 < C8_N; c0 += 16) {
        const int c = tid >> 4;
        const int u = (tid & 15) * 4;
        {
            const float4 t = *(const float4*)(q + (size_t)(c0 + c) * HW_N + i0 + u);
            Qs[c][u + 0] = t.x; Qs[c][u + 1] = t.y;
            Qs[c][u + 2] = t.z; Qs[c][u + 3] = t.w;
        }
        {
            const float4 t = *(const float4*)(k + (size_t)(c0 + c) * HW_N + j0 + u);
            Ks[c][u + 0] = t.x; Ks[c][u + 1] = t.y;
            Ks[c][u + 2] = t.z; Ks[c][u + 3] = t.w;
        }
        __syncthreads();
        #pragma unroll
        for (int cc = 0; cc < 16; ++cc) {
            float qi[4], kj[4];
            #pragma unroll
            for (int i = 0; i < 4; ++i) qi[i] = Qs[cc][ty * 4 + i];
            #pragma unroll
            for (int j = 0; j < 4; ++j) kj[j] = Ks[cc][tx * 4 + j];
            #pragma unroll
            for (int i = 0; i < 4; ++i)
                #pragma unroll
                for (int j = 0; j < 4; ++j)
                    acc[i][j] = fmaf(qi[i], kj[j], acc[i][j]);
        }
        __syncthreads();
    }

    #pragma unroll
    for (int i = 0; i < 4; ++i) {
        float4 r;
        r.x = acc[i][0]; r.y = acc[i][1]; r.z = acc[i][2]; r.w = acc[i][3];
        *(float4*)(att + ((size_t)b * HW_N + i0 + ty * 4 + i) * HW_N + j0 + tx * 4) = r;
    }
}

// ---------------------------------------------------------------------------
// Kernel 3: row softmax in place (unchanged).
// ---------------------------------------------------------------------------
__global__ __launch_bounds__(256) void softmax_kernel(float* __restrict__ att)
{
    const size_t row = blockIdx.x;                 // b*HW + i
    float* e = att + row * (size_t)HW_N;
    const int tid  = threadIdx.x;
    const int wv_  = tid >> 6;                     // wave id (wave64)
    const int lane = tid & 63;

    float4 v = ((const float4*)e)[tid];

    float m = fmaxf(fmaxf(v.x, v.y), fmaxf(v.z, v.w));
    #pragma unroll
    for (int off = 32; off > 0; off >>= 1)
        m = fmaxf(m, __shfl_down(m, off, 64));
    __shared__ float red[4];
    if (lane == 0) red[wv_] = m;
    __syncthreads();
    m = fmaxf(fmaxf(red[0], red[1]), fmaxf(red[2], red[3]));
    __syncthreads();   // red reused below

    float4 ex;
    ex.x = __expf(v.x - m); ex.y = __expf(v.y - m);
    ex.z = __expf(v.z - m); ex.w = __expf(v.w - m);
    float s = ex.x + ex.y + ex.z + ex.w;
    #pragma unroll
    for (int off = 32; off > 0; off >>= 1)
        s += __shfl_down(s, off, 64);
    if (lane == 0) red[wv_] = s;
    __syncthreads();
    s = red[0] + red[1] + red[2] + red[3];

    const float inv = 1.0f / s;
    ex.x *= inv; ex.y *= inv; ex.z *= inv; ex.w *= inv;
    ((float4*)e)[tid] = ex;
}

// ---------------------------------------------------------------------------
// Kernel 4 (REWRITTEN): out[b,c,i] = sum_j v[b,c,j] * att[b,i,j] via bf16 MFMA.
// GEMM per batch: M=512 (c), N=1024 (i), K=1024 (j); both operands K-contig.
// 128x128 block tile, BK=64, 4 waves each computing a 64x64 sub-tile with
// mfma_f32_16x16x32_bf16 (fp32 accumulation).  fp32 operands are reg-staged,
// converted to bf16 (RNE) and stored to XOR-swizzled LDS:
//   16B chunk c of row r lives at chunk position (c ^ (r&7))  -> conflict-free
//   ds_write_b128 and conflict-free bf16x8 fragment ds_read_b128.
// Fragment layouts (guide §3, verified m89/m91/m92):
//   A: lane l supplies A[l&15][(l>>4)*8 + e]   (8 contiguous K)
//   B: lane l supplies B[(l>>4)*8 + e][l&15]   = att[i=l&15][8 contiguous j]
//   C/D: row = (l>>4)*4 + reg, col = l&15
// Epilogue fused: rgb = g*out + x ; hho = g*out + hha.
// ---------------------------------------------------------------------------
__global__ __launch_bounds__(256) void out_kernel(
    const float* __restrict__ qkv, const float* __restrict__ att,
    const float* __restrict__ x, const float* __restrict__ hha,
    const float* __restrict__ gamma,
    float* __restrict__ rgb, float* __restrict__ hho)
{
    const int b   = blockIdx.z;
    const int c0  = blockIdx.y * 128;
    const int i0  = blockIdx.x * 128;
    const int tid = threadIdx.x;

    const float* vptr = qkv + ((size_t)b * MQKV + 128) * HW_N + (size_t)c0 * HW_N;
    const float* aptr = att + (size_t)b * HW_N * HW_N + (size_t)i0 * HW_N;

    __shared__ __align__(16) unsigned short Vs[128 * 64];  // [c-row][j] bf16, swizzled
    __shared__ __align__(16) unsigned short Ps[128 * 64];  // [i-row][j] bf16, swizzled

    // staging decomposition: thread -> (16B chunk sq, base row sr), 4 rows apart by 32
    const int sq = tid & 7;           // chunk (8 bf16 = 8 fp32 source) within 64-col row
    const int sr = tid >> 3;          // 0..31

    // wave decomposition: 4 waves -> 2x2 grid of 64x64 sub-tiles
    const int lane = tid & 63;
    const int wave = tid >> 6;
    const int wrow = (wave >> 1) * 64;   // c offset within block tile
    const int wcol = (wave & 1) * 64;    // i offset within block tile
    const int lrow = lane & 15;
    const int lk   = lane >> 4;          // 0..3 (K-group)

    f32x4 acc[4][4] = {};
    float4 ra[4][2], rb[4][2];           // in-flight fp32 staging (next K-slab)

    auto load_tiles = [&](int j0) {
        #pragma unroll
        for (int s = 0; s < 4; ++s) {
            const float* pa = vptr + (size_t)(sr + 32 * s) * HW_N + j0 + sq * 8;
            ra[s][0] = *(const float4*)(pa);
            ra[s][1] = *(const float4*)(pa + 4);
            const float* pb = aptr + (size_t)(sr + 32 * s) * HW_N + j0 + sq * 8;
            rb[s][0] = *(const float4*)(pb);
            rb[s][1] = *(const float4*)(pb + 4);
        }
    };

    auto write_tiles = [&]() {
        #pragma unroll
        for (int s = 0; s < 4; ++s) {
            const int r  = sr + 32 * s;
            const int ch = sq ^ (r & 7);
            uint4 wa, wb;
            wa.x = pack2_bf16(ra[s][0].x, ra[s][0].y);
            wa.y = pack2_bf16(ra[s][0].z, ra[s][0].w);
            wa.z = pack2_bf16(ra[s][1].x, ra[s][1].y);
            wa.w = pack2_bf16(ra[s][1].z, ra[s][1].w);
            wb.x = pack2_bf16(rb[s][0].x, rb[s][0].y);
            wb.y = pack2_bf16(rb[s][0].z, rb[s][0].w);
            wb.z = pack2_bf16(rb[s][1].x, rb[s][1].y);
            wb.w = pack2_bf16(rb[s][1].z, rb[s][1].w);
            *reinterpret_cast<uint4*>(&Vs[r * 64 + ch * 8]) = wa;
            *reinterpret_cast<uint4*>(&Ps[r * 64 + ch * 8]) = wb;
        }
    };

    load_tiles(0);
    for (int jt = 0; jt < HW_N / 64; ++jt) {
        __syncthreads();               // previous compute done, LDS free
        write_tiles();
        __syncthreads();               // tiles visible
        if (jt + 1 < HW_N / 64) load_tiles((jt + 1) * 64);  // overlap with MFMA

        #pragma unroll
        for (int kb = 0; kb < 2; ++kb) {
            bf16x8 af[4], bf[4];
            #pragma unroll
            for (int m = 0; m < 4; ++m) {
                const int r  = wrow + m * 16 + lrow;         // r&7 == lrow&7
                const int ch = (kb * 4 + lk) ^ (lrow & 7);
                af[m] = *reinterpret_cast<const bf16x8*>(&Vs[r * 64 + ch * 8]);
            }
            #pragma unroll
            for (int n = 0; n < 4; ++n) {
                const int r  = wcol + n * 16 + lrow;
                const int ch = (kb * 4 + lk) ^ (lrow & 7);
                bf[n] = *reinterpret_cast<const bf16x8*>(&Ps[r * 64 + ch * 8]);
            }
            #pragma unroll
            for (int m = 0; m < 4; ++m)
                #pragma unroll
                for (int n = 0; n < 4; ++n)
                    acc[m][n] = __builtin_amdgcn_mfma_f32_16x16x32_bf16(
                        af[m], bf[n], acc[m][n], 0, 0, 0);
        }
    }

    // epilogue: C/D layout row=(lane>>4)*4+reg (c), col=lane&15 (i)
    const float g    = gamma[0];
    const int   crow = c0 + wrow + lk * 4;
    const int   icol = i0 + wcol + lrow;
    #pragma unroll
    for (int m = 0; m < 4; ++m) {
        #pragma unroll
        for (int rr = 0; rr < 4; ++rr) {
            const int c = crow + m * 16 + rr;
            const size_t base = ((size_t)b * C_N + c) * HW_N + icol;
            #pragma unroll
            for (int n = 0; n < 4; ++n) {
                const float o  = acc[m][n][rr];
                const float xv = x[base + n * 16];
                const float hv = hha[base + n * 16];
                rgb[base + n * 16] = fmaf(g, o, xv);
                hho[base + n * 16] = fmaf(g, o, hv);
            }
        }
    }
}

// ---------------------------------------------------------------------------
extern "C" void kernel_launch(void* const* d_in, const int* in_sizes, int n_in,
                              void* d_out, int out_size, void* d_ws, size_t ws_size,
                              hipStream_t stream)
{
    const float* x     = (const float*)d_in[0];
    const float* hha   = (const float*)d_in[1];
    const float* wq    = (const float*)d_in[2];
    const float* bq    = (const float*)d_in[3];
    const float* wk    = (const float*)d_in[4];
    const float* bk    = (const float*)d_in[5];
    const float* wv    = (const float*)d_in[6];
    const float* bv    = (const float*)d_in[7];
    const float* gamma = (const float*)d_in[8];

    float* out = (float*)d_out;
    float* att = out;                                        // [32,1024,1024]
    float* rgb = att + (size_t)B_N * HW_N * HW_N;            // [32,512,1024]
    float* hho = rgb + (size_t)B_N * C_N * HW_N;             // [32,512,1024]

    float* qkv = (float*)d_ws;   // [32,640,1024] floats = 80 MiB scratch

    qkv_proj_kernel<<<dim3(HW_N / 64, MQKV / 64, B_N), 256, 0, stream>>>(
        x, wq, bq, wk, bk, wv, bv, qkv);
    energy_kernel<<<dim3(HW_N / 64, HW_N / 64, B_N), 256, 0, stream>>>(qkv, att);
    softmax_kernel<<<dim3(B_N * HW_N), 256, 0, stream>>>(att);
    out_kernel<<<dim3(HW_N / 128, C_N / 128, B_N), 256, 0, stream>>>(
        qkv, att, x, hha, gamma, rgb, hho);
}

// Round 2
// 721.547 us; speedup vs baseline: 1.9832x; 1.3033x over previous
//
#include <hip/hip_runtime.h>

// Problem constants (B,C,H,W = 32,512,32,32)
#define B_N   32
#define C_N   512
#define HW_N  1024
#define C8_N  64

typedef short bf16x8 __attribute__((ext_vector_type(8)));
typedef float f32x4  __attribute__((ext_vector_type(4)));

// round-to-nearest-even fp32 -> bf16 bits (low 16 of result)
static __device__ __forceinline__ unsigned int bf16_bits(float a)
{
    unsigned int u = __float_as_uint(a);
    return (u + 0x7fffu + ((u >> 16) & 1u)) >> 16;
}

// two fp32 -> packed bf16 pair (elem0 low, elem1 high)
static __device__ __forceinline__ unsigned int pack2_bf16(float a, float b)
{
    return bf16_bits(a) | (bf16_bits(b) << 16);
}

// ---------------------------------------------------------------------------
// Kernel 0: transpose + two-term bf16 split of x.
// x[b,c,p] fp32  ->  xt[b,p,c] u32 = (hi<<16)|lo  where x ~= hi + lo (bf16 each)
// xt lives in the att region of d_out (overwritten later by energy_kernel).
// ---------------------------------------------------------------------------
__global__ __launch_bounds__(256) void xsplit_transpose_kernel(
    const float* __restrict__ x, unsigned int* __restrict__ xt)
{
    const int b   = blockIdx.z;
    const int c0  = blockIdx.y * 64;
    const int p0  = blockIdx.x * 64;
    const int tid = threadIdx.x;

    __shared__ unsigned int Ls[64][65];

    const float* xb = x + ((size_t)b * C_N + c0) * HW_N + p0;
    {
        const int c = tid >> 4;            // 0..15
        const int p = (tid & 15) * 4;
        #pragma unroll
        for (int s = 0; s < 4; ++s) {
            const float4 t = *(const float4*)(xb + (size_t)(c + 16 * s) * HW_N + p);
            const float v[4] = { t.x, t.y, t.z, t.w };
            #pragma unroll
            for (int j = 0; j < 4; ++j) {
                const unsigned int hi = bf16_bits(v[j]);
                const float hif = __uint_as_float(hi << 16);
                const unsigned int lo = bf16_bits(v[j] - hif);
                Ls[c + 16 * s][p + j] = (hi << 16) | lo;
            }
        }
    }
    __syncthreads();
    unsigned int* xo = xt + ((size_t)b * HW_N + p0) * C_N + c0;
    {
        const int p = tid >> 4;
        const int c = (tid & 15) * 4;
        #pragma unroll
        for (int s = 0; s < 4; ++s) {
            uint4 r;
            r.x = Ls[c + 0][p + 16 * s];
            r.y = Ls[c + 1][p + 16 * s];
            r.z = Ls[c + 2][p + 16 * s];
            r.w = Ls[c + 3][p + 16 * s];
            *(uint4*)(xo + (size_t)(p + 16 * s) * C_N + c) = r;
        }
    }
}

// ---------------------------------------------------------------------------
// Kernel 1: QKV projection via bf16 MFMA with split-precision.
// GEMM per batch: M=640 (rows: 64 q + 64 k + 512 v), N=1024 (pixels), K=512.
// blockIdx.y==0 -> q+k tile (3-product split: Whi*xhi + Whi*xlo + Wlo*xhi,
//                  fp32-grade, written fp32 to qk buffer)
// blockIdx.y>=1 -> v tiles (2-product: Whi*(xhi+xlo), written bf16 to vout)
// Structure cloned from the verified out_kernel: 128x128 tile, BK=64,
// 4 waves of 64x64, XOR-swizzled LDS (16B chunk ch -> ch ^ (row&7)).
// ---------------------------------------------------------------------------
__global__ __launch_bounds__(256) void qkv_mfma_kernel(
    const unsigned int* __restrict__ xt,
    const float* __restrict__ wq, const float* __restrict__ bq,
    const float* __restrict__ wk, const float* __restrict__ bk,
    const float* __restrict__ wv, const float* __restrict__ bv,
    float* __restrict__ qk, unsigned short* __restrict__ vout)
{
    const int b    = blockIdx.z;
    const int by   = blockIdx.y;          // 0 = q+k, 1..4 = v
    const int p0   = blockIdx.x * 128;
    const int tid  = threadIdx.x;
    const bool qkblk = (by == 0);

    __shared__ __align__(16) unsigned short AsHi[128 * 64];
    __shared__ __align__(16) unsigned short AsLo[128 * 64];
    __shared__ __align__(16) unsigned short BsHi[128 * 64];
    __shared__ __align__(16) unsigned short BsLo[128 * 64];

    const int sq = tid & 7;               // 16B chunk within 64-wide K slab
    const int sr = tid >> 3;              // 0..31 (4 slabs of 32 rows)

    const int lane = tid & 63;
    const int wave = tid >> 6;
    const int wrow = (wave >> 1) * 64;    // m offset within tile
    const int wcol = (wave & 1) * 64;     // p offset within tile
    const int lrow = lane & 15;
    const int lk   = lane >> 4;

    const unsigned int* bt = xt + ((size_t)b * HW_N + p0) * C_N;  // [128 p][512 c]

    f32x4 acc[4][4] = {};
    float4 ra[4][2];
    uint4  rb[4][2];

    auto wrowptr = [&](int r) -> const float* {
        if (qkblk) return (r < 64) ? (wq + (size_t)r * C_N)
                                   : (wk + (size_t)(r - 64) * C_N);
        return wv + (size_t)((by - 1) * 128 + r) * C_N;
    };

    auto load_tiles = [&](int k0) {
        #pragma unroll
        for (int s = 0; s < 4; ++s) {
            const int r = sr + 32 * s;
            const float* pa = wrowptr(r) + k0 + sq * 8;
            ra[s][0] = *(const float4*)(pa);
            ra[s][1] = *(const float4*)(pa + 4);
            const unsigned int* pb = bt + (size_t)r * C_N + k0 + sq * 8;
            rb[s][0] = *(const uint4*)(pb);
            rb[s][1] = *(const uint4*)(pb + 4);
        }
    };

    auto write_tiles = [&]() {
        #pragma unroll
        for (int s = 0; s < 4; ++s) {
            const int r  = sr + 32 * s;
            const int ch = sq ^ (r & 7);
            // A (W fp32) -> hi/lo bf16
            const float e[8] = { ra[s][0].x, ra[s][0].y, ra[s][0].z, ra[s][0].w,
                                 ra[s][1].x, ra[s][1].y, ra[s][1].z, ra[s][1].w };
            unsigned int h[8];
            #pragma unroll
            for (int j = 0; j < 8; ++j) h[j] = bf16_bits(e[j]);
            uint4 ah;
            ah.x = h[0] | (h[1] << 16); ah.y = h[2] | (h[3] << 16);
            ah.z = h[4] | (h[5] << 16); ah.w = h[6] | (h[7] << 16);
            *reinterpret_cast<uint4*>(&AsHi[r * 64 + ch * 8]) = ah;
            if (qkblk) {
                unsigned int l[8];
                #pragma unroll
                for (int j = 0; j < 8; ++j) {
                    const float hf = __uint_as_float(h[j] << 16);
                    l[j] = bf16_bits(e[j] - hf);
                }
                uint4 al;
                al.x = l[0] | (l[1] << 16); al.y = l[2] | (l[3] << 16);
                al.z = l[4] | (l[5] << 16); al.w = l[6] | (l[7] << 16);
                *reinterpret_cast<uint4*>(&AsLo[r * 64 + ch * 8]) = al;
            }
            // B (xt packed u32) -> hi/lo bf16
            const unsigned int q0[8] = { rb[s][0].x, rb[s][0].y, rb[s][0].z, rb[s][0].w,
                                         rb[s][1].x, rb[s][1].y, rb[s][1].z, rb[s][1].w };
            uint4 bh, bl;
            bh.x = (q0[0] >> 16) | (q0[1] & 0xffff0000u);
            bh.y = (q0[2] >> 16) | (q0[3] & 0xffff0000u);
            bh.z = (q0[4] >> 16) | (q0[5] & 0xffff0000u);
            bh.w = (q0[6] >> 16) | (q0[7] & 0xffff0000u);
            bl.x = (q0[0] & 0xffffu) | (q0[1] << 16);
            bl.y = (q0[2] & 0xffffu) | (q0[3] << 16);
            bl.z = (q0[4] & 0xffffu) | (q0[5] << 16);
            bl.w = (q0[6] & 0xffffu) | (q0[7] << 16);
            *reinterpret_cast<uint4*>(&BsHi[r * 64 + ch * 8]) = bh;
            *reinterpret_cast<uint4*>(&BsLo[r * 64 + ch * 8]) = bl;
        }
    };

    load_tiles(0);
    for (int kt = 0; kt < C_N / 64; ++kt) {
        __syncthreads();
        write_tiles();
        __syncthreads();
        if (kt + 1 < C_N / 64) load_tiles((kt + 1) * 64);

        #pragma unroll
        for (int kb = 0; kb < 2; ++kb) {
            bf16x8 bfh[4], bfl[4];
            #pragma unroll
            for (int n = 0; n < 4; ++n) {
                const int r  = wcol + n * 16 + lrow;
                const int ch = (kb * 4 + lk) ^ (lrow & 7);
                bfh[n] = *reinterpret_cast<const bf16x8*>(&BsHi[r * 64 + ch * 8]);
                bfl[n] = *reinterpret_cast<const bf16x8*>(&BsLo[r * 64 + ch * 8]);
            }
            #pragma unroll
            for (int m = 0; m < 4; ++m) {
                const int r  = wrow + m * 16 + lrow;
                const int ch = (kb * 4 + lk) ^ (lrow & 7);
                const bf16x8 ah = *reinterpret_cast<const bf16x8*>(&AsHi[r * 64 + ch * 8]);
                #pragma unroll
                for (int n = 0; n < 4; ++n) {
                    acc[m][n] = __builtin_amdgcn_mfma_f32_16x16x32_bf16(ah, bfh[n], acc[m][n], 0, 0, 0);
                    acc[m][n] = __builtin_amdgcn_mfma_f32_16x16x32_bf16(ah, bfl[n], acc[m][n], 0, 0, 0);
                }
                if (qkblk) {
                    const bf16x8 al = *reinterpret_cast<const bf16x8*>(&AsLo[r * 64 + ch * 8]);
                    #pragma unroll
                    for (int n = 0; n < 4; ++n)
                        acc[m][n] = __builtin_amdgcn_mfma_f32_16x16x32_bf16(al, bfh[n], acc[m][n], 0, 0, 0);
                }
            }
        }
    }

    // epilogue: C/D row = (lane>>4)*4 + reg (m), col = lane&15 (p)
    #pragma unroll
    for (int m = 0; m < 4; ++m) {
        #pragma unroll
        for (int rr = 0; rr < 4; ++rr) {
            const int r = wrow + m * 16 + lk * 4 + rr;   // tile row 0..127
            if (qkblk) {
                const float bi = (r < 64) ? bq[r] : bk[r - 64];
                float* dst = qk + ((size_t)b * 128 + r) * HW_N + p0 + wcol + lrow;
                #pragma unroll
                for (int n = 0; n < 4; ++n)
                    dst[n * 16] = acc[m][n][rr] + bi;
            } else {
                const int vr = (by - 1) * 128 + r;
                const float bi = bv[vr];
                unsigned short* dst = vout + ((size_t)b * C_N + vr) * HW_N + p0 + wcol + lrow;
                #pragma unroll
                for (int n = 0; n < 4; ++n)
                    dst[n * 16] = (unsigned short)bf16_bits(acc[m][n][rr] + bi);
            }
        }
    }
}

// ---------------------------------------------------------------------------
// Kernel 2: energy[b,i,j] = sum_c q[b,c,i] * k[b,c,j]  (fp32 exact)
// q/k now live in the compact qk buffer [b][128][1024].
// ---------------------------------------------------------------------------
__global__ __launch_bounds__(256) void energy_kernel(
    const float* __restrict__ qkbuf, float* __restrict__ att)
{
    const int b   = blockIdx.z;
    const int i0  = blockIdx.y * 64;
    const int j0  = blockIdx.x * 64;
    const int tid = threadIdx.x;
    const int tx  = tid & 15;
    const int ty  = tid >> 4;

    const float* q = qkbuf + (size_t)b * 128 * HW_N;  // [64][1024]
    const float* k = q + (size_t)C8_N * HW_N;         // [64][1024]

    __shared__ float Qs[16][65];
    __shared__ float Ks[16][65];
    float acc[4][4] = {};

    for (int c0 = 0; c0 < C8_N; c0 += 16) {
        const int c = tid >> 4;
        const int u = (tid & 15) * 4;
        {
            const float4 t = *(const float4*)(q + (size_t)(c0 + c) * HW_N + i0 + u);
            Qs[c][u + 0] = t.x; Qs[c][u + 1] = t.y;
            Qs[c][u + 2] = t.z; Qs[c][u + 3] = t.w;
        }
        {
            const float4 t = *(const float4*)(k + (size_t)(c0 + c) * HW_N + j0 + u);
            Ks[c][u + 0] = t.x; Ks[c][u + 1] = t.y;
            Ks[c][u + 2] = t.z; Ks[c][u + 3] = t.w;
        }
        __syncthreads();
        #pragma unroll
        for (int cc = 0; cc < 16; ++cc) {
            float qi[4], kj[4];
            #pragma unroll
            for (int i = 0; i < 4; ++i) qi[i] = Qs[cc][ty * 4 + i];
            #pragma unroll
            for (int j = 0; j < 4; ++j) kj[j] = Ks[cc][tx * 4 + j];
            #pragma unroll
            for (int i = 0; i < 4; ++i)
                #pragma unroll
                for (int j = 0; j < 4; ++j)
                    acc[i][j] = fmaf(qi[i], kj[j], acc[i][j]);
        }
        __syncthreads();
    }

    #pragma unroll
    for (int i = 0; i < 4; ++i) {
        float4 r;
        r.x = acc[i][0]; r.y = acc[i][1]; r.z = acc[i][2]; r.w = acc[i][3];
        *(float4*)(att + ((size_t)b * HW_N + i0 + ty * 4 + i) * HW_N + j0 + tx * 4) = r;
    }
}

// ---------------------------------------------------------------------------
// Kernel 3: row softmax in place (unchanged).
// ---------------------------------------------------------------------------
__global__ __launch_bounds__(256) void softmax_kernel(float* __restrict__ att)
{
    const size_t row = blockIdx.x;
    float* e = att + row * (size_t)HW_N;
    const int tid  = threadIdx.x;
    const int wv_  = tid >> 6;
    const int lane = tid & 63;

    float4 v = ((const float4*)e)[tid];

    float m = fmaxf(fmaxf(v.x, v.y), fmaxf(v.z, v.w));
    #pragma unroll
    for (int off = 32; off > 0; off >>= 1)
        m = fmaxf(m, __shfl_down(m, off, 64));
    __shared__ float red[4];
    if (lane == 0) red[wv_] = m;
    __syncthreads();
    m = fmaxf(fmaxf(red[0], red[1]), fmaxf(red[2], red[3]));
    __syncthreads();

    float4 ex;
    ex.x = __expf(v.x - m); ex.y = __expf(v.y - m);
    ex.z = __expf(v.z - m); ex.w = __expf(v.w - m);
    float s = ex.x + ex.y + ex.z + ex.w;
    #pragma unroll
    for (int off = 32; off > 0; off >>= 1)
        s += __shfl_down(s, off, 64);
    if (lane == 0) red[wv_] = s;
    __syncthreads();
    s = red[0] + red[1] + red[2] + red[3];

    const float inv = 1.0f / s;
    ex.x *= inv; ex.y *= inv; ex.z *= inv; ex.w *= inv;
    ((float4*)e)[tid] = ex;
}

// ---------------------------------------------------------------------------
// Kernel 4: out[b,c,i] = sum_j v[b,c,j] * att[b,i,j] via bf16 MFMA.
// v is now pre-converted bf16 (vout) -> A-side staging loads 16B/8-elems and
// needs no conversion.  B (att) staged fp32->bf16 as before.
// ---------------------------------------------------------------------------
__global__ __launch_bounds__(256) void out_kernel(
    const unsigned short* __restrict__ vout, const float* __restrict__ att,
    const float* __restrict__ x, const float* __restrict__ hha,
    const float* __restrict__ gamma,
    float* __restrict__ rgb, float* __restrict__ hho)
{
    const int b   = blockIdx.z;
    const int c0  = blockIdx.y * 128;
    const int i0  = blockIdx.x * 128;
    const int tid = threadIdx.x;

    const unsigned short* vptr = vout + (size_t)(b * C_N + c0) * HW_N;
    const float* aptr = att + (size_t)b * HW_N * HW_N + (size_t)i0 * HW_N;

    __shared__ __align__(16) unsigned short Vs[128 * 64];
    __shared__ __align__(16) unsigned short Ps[128 * 64];

    const int sq = tid & 7;
    const int sr = tid >> 3;

    const int lane = tid & 63;
    const int wave = tid >> 6;
    const int wrow = (wave >> 1) * 64;
    const int wcol = (wave & 1) * 64;
    const int lrow = lane & 15;
    const int lk   = lane >> 4;

    f32x4 acc[4][4] = {};
    uint4  ra[4];          // bf16 x8 A staging
    float4 rb[4][2];       // fp32 B staging

    auto load_tiles = [&](int j0) {
        #pragma unroll
        for (int s = 0; s < 4; ++s) {
            ra[s] = *(const uint4*)(vptr + (size_t)(sr + 32 * s) * HW_N + j0 + sq * 8);
            const float* pb = aptr + (size_t)(sr + 32 * s) * HW_N + j0 + sq * 8;
            rb[s][0] = *(const float4*)(pb);
            rb[s][1] = *(const float4*)(pb + 4);
        }
    };

    auto write_tiles = [&]() {
        #pragma unroll
        for (int s = 0; s < 4; ++s) {
            const int r  = sr + 32 * s;
            const int ch = sq ^ (r & 7);
            *reinterpret_cast<uint4*>(&Vs[r * 64 + ch * 8]) = ra[s];
            uint4 wb;
            wb.x = pack2_bf16(rb[s][0].x, rb[s][0].y);
            wb.y = pack2_bf16(rb[s][0].z, rb[s][0].w);
            wb.z = pack2_bf16(rb[s][1].x, rb[s][1].y);
            wb.w = pack2_bf16(rb[s][1].z, rb[s][1].w);
            *reinterpret_cast<uint4*>(&Ps[r * 64 + ch * 8]) = wb;
        }
    };

    load_tiles(0);
    for (int jt = 0; jt < HW_N / 64; ++jt) {
        __syncthreads();
        write_tiles();
        __syncthreads();
        if (jt + 1 < HW_N / 64) load_tiles((jt + 1) * 64);

        #pragma unroll
        for (int kb = 0; kb < 2; ++kb) {
            bf16x8 af[4], bf[4];
            #pragma unroll
            for (int m = 0; m < 4; ++m) {
                const int r  = wrow + m * 16 + lrow;
                const int ch = (kb * 4 + lk) ^ (lrow & 7);
                af[m] = *reinterpret_cast<const bf16x8*>(&Vs[r * 64 + ch * 8]);
            }
            #pragma unroll
            for (int n = 0; n < 4; ++n) {
                const int r  = wcol + n * 16 + lrow;
                const int ch = (kb * 4 + lk) ^ (lrow & 7);
                bf[n] = *reinterpret_cast<const bf16x8*>(&Ps[r * 64 + ch * 8]);
            }
            #pragma unroll
            for (int m = 0; m < 4; ++m)
                #pragma unroll
                for (int n = 0; n < 4; ++n)
                    acc[m][n] = __builtin_amdgcn_mfma_f32_16x16x32_bf16(
                        af[m], bf[n], acc[m][n], 0, 0, 0);
        }
    }

    const float g    = gamma[0];
    const int   crow = c0 + wrow + lk * 4;
    const int   icol = i0 + wcol + lrow;
    #pragma unroll
    for (int m = 0; m < 4; ++m) {
        #pragma unroll
        for (int rr = 0; rr < 4; ++rr) {
            const int c = crow + m * 16 + rr;
            const size_t base = ((size_t)b * C_N + c) * HW_N + icol;
            #pragma unroll
            for (int n = 0; n < 4; ++n) {
                const float o  = acc[m][n][rr];
                const float xv = x[base + n * 16];
                const float hv = hha[base + n * 16];
                rgb[base + n * 16] = fmaf(g, o, xv);
                hho[base + n * 16] = fmaf(g, o, hv);
            }
        }
    }
}

// ---------------------------------------------------------------------------
extern "C" void kernel_launch(void* const* d_in, const int* in_sizes, int n_in,
                              void* d_out, int out_size, void* d_ws, size_t ws_size,
                              hipStream_t stream)
{
    const float* x     = (const float*)d_in[0];
    const float* hha   = (const float*)d_in[1];
    const float* wq    = (const float*)d_in[2];
    const float* bq    = (const float*)d_in[3];
    const float* wk    = (const float*)d_in[4];
    const float* bk    = (const float*)d_in[5];
    const float* wv    = (const float*)d_in[6];
    const float* bv    = (const float*)d_in[7];
    const float* gamma = (const float*)d_in[8];

    float* out = (float*)d_out;
    float* att = out;                                        // [32,1024,1024]
    float* rgb = att + (size_t)B_N * HW_N * HW_N;            // [32,512,1024]
    float* hho = rgb + (size_t)B_N * C_N * HW_N;             // [32,512,1024]

    // workspace: qk fp32 [32][128][1024] (16 MiB) + v bf16 [32][512][1024] (32 MiB)
    float*          qkbuf = (float*)d_ws;
    unsigned short* vbuf  = (unsigned short*)((float*)d_ws + (size_t)B_N * 128 * HW_N);

    // xT split lives in the (not yet written) att region: 64 MiB of 128 MiB
    unsigned int* xt = (unsigned int*)att;

    xsplit_transpose_kernel<<<dim3(HW_N / 64, C_N / 64, B_N), 256, 0, stream>>>(x, xt);
    qkv_mfma_kernel<<<dim3(HW_N / 128, 5, B_N), 256, 0, stream>>>(
        xt, wq, bq, wk, bk, wv, bv, qkbuf, vbuf);
    energy_kernel<<<dim3(HW_N / 64, HW_N / 64, B_N), 256, 0, stream>>>(qkbuf, att);
    softmax_kernel<<<dim3(B_N * HW_N), 256, 0, stream>>>(att);
    out_kernel<<<dim3(HW_N / 128, C_N / 128, B_N), 256, 0, stream>>>(
        vbuf, att, x, hha, gamma, rgb, hho);
}

// Round 3
// 677.962 us; speedup vs baseline: 2.1107x; 1.0643x over previous
//
#include <hip/hip_runtime.h>

// Problem constants (B,C,H,W = 32,512,32,32)
#define B_N   32
#define C_N   512
#define HW_N  1024
#define C8_N  64

typedef short bf16x8 __attribute__((ext_vector_type(8)));
typedef float f32x4  __attribute__((ext_vector_type(4)));

// round-to-nearest-even fp32 -> bf16 bits (low 16 of result)
static __device__ __forceinline__ unsigned int bf16_bits(float a)
{
    unsigned int u = __float_as_uint(a);
    return (u + 0x7fffu + ((u >> 16) & 1u)) >> 16;
}

// two fp32 -> packed bf16 pair (elem0 low, elem1 high)
static __device__ __forceinline__ unsigned int pack2_bf16(float a, float b)
{
    return bf16_bits(a) | (bf16_bits(b) << 16);
}

// ---------------------------------------------------------------------------
// Kernel 0: transpose + two-term bf16 split of x.
// x[b,c,p] fp32  ->  xt[b,p,c] u32 = (hi<<16)|lo  where x ~= hi + lo (bf16 each)
// xt lives in the att region of d_out (overwritten later by energy_mfma).
// ---------------------------------------------------------------------------
__global__ __launch_bounds__(256) void xsplit_transpose_kernel(
    const float* __restrict__ x, unsigned int* __restrict__ xt)
{
    const int b   = blockIdx.z;
    const int c0  = blockIdx.y * 64;
    const int p0  = blockIdx.x * 64;
    const int tid = threadIdx.x;

    __shared__ unsigned int Ls[64][65];

    const float* xb = x + ((size_t)b * C_N + c0) * HW_N + p0;
    {
        const int c = tid >> 4;            // 0..15
        const int p = (tid & 15) * 4;
        #pragma unroll
        for (int s = 0; s < 4; ++s) {
            const float4 t = *(const float4*)(xb + (size_t)(c + 16 * s) * HW_N + p);
            const float v[4] = { t.x, t.y, t.z, t.w };
            #pragma unroll
            for (int j = 0; j < 4; ++j) {
                const unsigned int hi = bf16_bits(v[j]);
                const float hif = __uint_as_float(hi << 16);
                const unsigned int lo = bf16_bits(v[j] - hif);
                Ls[c + 16 * s][p + j] = (hi << 16) | lo;
            }
        }
    }
    __syncthreads();
    unsigned int* xo = xt + ((size_t)b * HW_N + p0) * C_N + c0;
    {
        const int p = tid >> 4;
        const int c = (tid & 15) * 4;
        #pragma unroll
        for (int s = 0; s < 4; ++s) {
            uint4 r;
            r.x = Ls[c + 0][p + 16 * s];
            r.y = Ls[c + 1][p + 16 * s];
            r.z = Ls[c + 2][p + 16 * s];
            r.w = Ls[c + 3][p + 16 * s];
            *(uint4*)(xo + (size_t)(p + 16 * s) * C_N + c) = r;
        }
    }
}

// ---------------------------------------------------------------------------
// Kernel 1: QKV projection via bf16 MFMA with split-precision (unchanged).
// ---------------------------------------------------------------------------
__global__ __launch_bounds__(256) void qkv_mfma_kernel(
    const unsigned int* __restrict__ xt,
    const float* __restrict__ wq, const float* __restrict__ bq,
    const float* __restrict__ wk, const float* __restrict__ bk,
    const float* __restrict__ wv, const float* __restrict__ bv,
    float* __restrict__ qk, unsigned short* __restrict__ vout)
{
    const int b    = blockIdx.z;
    const int by   = blockIdx.y;          // 0 = q+k, 1..4 = v
    const int p0   = blockIdx.x * 128;
    const int tid  = threadIdx.x;
    const bool qkblk = (by == 0);

    __shared__ __align__(16) unsigned short AsHi[128 * 64];
    __shared__ __align__(16) unsigned short AsLo[128 * 64];
    __shared__ __align__(16) unsigned short BsHi[128 * 64];
    __shared__ __align__(16) unsigned short BsLo[128 * 64];

    const int sq = tid & 7;               // 16B chunk within 64-wide K slab
    const int sr = tid >> 3;              // 0..31 (4 slabs of 32 rows)

    const int lane = tid & 63;
    const int wave = tid >> 6;
    const int wrow = (wave >> 1) * 64;    // m offset within tile
    const int wcol = (wave & 1) * 64;     // p offset within tile
    const int lrow = lane & 15;
    const int lk   = lane >> 4;

    const unsigned int* bt = xt + ((size_t)b * HW_N + p0) * C_N;  // [128 p][512 c]

    f32x4 acc[4][4] = {};
    float4 ra[4][2];
    uint4  rb[4][2];

    auto wrowptr = [&](int r) -> const float* {
        if (qkblk) return (r < 64) ? (wq + (size_t)r * C_N)
                                   : (wk + (size_t)(r - 64) * C_N);
        return wv + (size_t)((by - 1) * 128 + r) * C_N;
    };

    auto load_tiles = [&](int k0) {
        #pragma unroll
        for (int s = 0; s < 4; ++s) {
            const int r = sr + 32 * s;
            const float* pa = wrowptr(r) + k0 + sq * 8;
            ra[s][0] = *(const float4*)(pa);
            ra[s][1] = *(const float4*)(pa + 4);
            const unsigned int* pb = bt + (size_t)r * C_N + k0 + sq * 8;
            rb[s][0] = *(const uint4*)(pb);
            rb[s][1] = *(const uint4*)(pb + 4);
        }
    };

    auto write_tiles = [&]() {
        #pragma unroll
        for (int s = 0; s < 4; ++s) {
            const int r  = sr + 32 * s;
            const int ch = sq ^ (r & 7);
            const float e[8] = { ra[s][0].x, ra[s][0].y, ra[s][0].z, ra[s][0].w,
                                 ra[s][1].x, ra[s][1].y, ra[s][1].z, ra[s][1].w };
            unsigned int h[8];
            #pragma unroll
            for (int j = 0; j < 8; ++j) h[j] = bf16_bits(e[j]);
            uint4 ah;
            ah.x = h[0] | (h[1] << 16); ah.y = h[2] | (h[3] << 16);
            ah.z = h[4] | (h[5] << 16); ah.w = h[6] | (h[7] << 16);
            *reinterpret_cast<uint4*>(&AsHi[r * 64 + ch * 8]) = ah;
            if (qkblk) {
                unsigned int l[8];
                #pragma unroll
                for (int j = 0; j < 8; ++j) {
                    const float hf = __uint_as_float(h[j] << 16);
                    l[j] = bf16_bits(e[j] - hf);
                }
                uint4 al;
                al.x = l[0] | (l[1] << 16); al.y = l[2] | (l[3] << 16);
                al.z = l[4] | (l[5] << 16); al.w = l[6] | (l[7] << 16);
                *reinterpret_cast<uint4*>(&AsLo[r * 64 + ch * 8]) = al;
            }
            const unsigned int q0[8] = { rb[s][0].x, rb[s][0].y, rb[s][0].z, rb[s][0].w,
                                         rb[s][1].x, rb[s][1].y, rb[s][1].z, rb[s][1].w };
            uint4 bh, bl;
            bh.x = (q0[0] >> 16) | (q0[1] & 0xffff0000u);
            bh.y = (q0[2] >> 16) | (q0[3] & 0xffff0000u);
            bh.z = (q0[4] >> 16) | (q0[5] & 0xffff0000u);
            bh.w = (q0[6] >> 16) | (q0[7] & 0xffff0000u);
            bl.x = (q0[0] & 0xffffu) | (q0[1] << 16);
            bl.y = (q0[2] & 0xffffu) | (q0[3] << 16);
            bl.z = (q0[4] & 0xffffu) | (q0[5] << 16);
            bl.w = (q0[6] & 0xffffu) | (q0[7] << 16);
            *reinterpret_cast<uint4*>(&BsHi[r * 64 + ch * 8]) = bh;
            *reinterpret_cast<uint4*>(&BsLo[r * 64 + ch * 8]) = bl;
        }
    };

    load_tiles(0);
    for (int kt = 0; kt < C_N / 64; ++kt) {
        __syncthreads();
        write_tiles();
        __syncthreads();
        if (kt + 1 < C_N / 64) load_tiles((kt + 1) * 64);

        #pragma unroll
        for (int kb = 0; kb < 2; ++kb) {
            bf16x8 bfh[4], bfl[4];
            #pragma unroll
            for (int n = 0; n < 4; ++n) {
                const int r  = wcol + n * 16 + lrow;
                const int ch = (kb * 4 + lk) ^ (lrow & 7);
                bfh[n] = *reinterpret_cast<const bf16x8*>(&BsHi[r * 64 + ch * 8]);
                bfl[n] = *reinterpret_cast<const bf16x8*>(&BsLo[r * 64 + ch * 8]);
            }
            #pragma unroll
            for (int m = 0; m < 4; ++m) {
                const int r  = wrow + m * 16 + lrow;
                const int ch = (kb * 4 + lk) ^ (lrow & 7);
                const bf16x8 ah = *reinterpret_cast<const bf16x8*>(&AsHi[r * 64 + ch * 8]);
                #pragma unroll
                for (int n = 0; n < 4; ++n) {
                    acc[m][n] = __builtin_amdgcn_mfma_f32_16x16x32_bf16(ah, bfh[n], acc[m][n], 0, 0, 0);
                    acc[m][n] = __builtin_amdgcn_mfma_f32_16x16x32_bf16(ah, bfl[n], acc[m][n], 0, 0, 0);
                }
                if (qkblk) {
                    const bf16x8 al = *reinterpret_cast<const bf16x8*>(&AsLo[r * 64 + ch * 8]);
                    #pragma unroll
                    for (int n = 0; n < 4; ++n)
                        acc[m][n] = __builtin_amdgcn_mfma_f32_16x16x32_bf16(al, bfh[n], acc[m][n], 0, 0, 0);
                }
            }
        }
    }

    #pragma unroll
    for (int m = 0; m < 4; ++m) {
        #pragma unroll
        for (int rr = 0; rr < 4; ++rr) {
            const int r = wrow + m * 16 + lk * 4 + rr;   // tile row 0..127
            if (qkblk) {
                const float bi = (r < 64) ? bq[r] : bk[r - 64];
                float* dst = qk + ((size_t)b * 128 + r) * HW_N + p0 + wcol + lrow;
                #pragma unroll
                for (int n = 0; n < 4; ++n)
                    dst[n * 16] = acc[m][n][rr] + bi;
            } else {
                const int vr = (by - 1) * 128 + r;
                const float bi = bv[vr];
                unsigned short* dst = vout + ((size_t)b * C_N + vr) * HW_N + p0 + wcol + lrow;
                #pragma unroll
                for (int n = 0; n < 4; ++n)
                    dst[n * 16] = (unsigned short)bf16_bits(acc[m][n][rr] + bi);
            }
        }
    }
}

// ---------------------------------------------------------------------------
// Kernel 1b: transpose + two-term bf16 split of the qk buffer.
// qk[b][m=0..127][p] fp32  ->  qkT[b][p][m] u32 = (hi<<16)|lo
//   cols 0..63 = q channels, 64..127 = k channels.  Makes both energy MFMA
//   operands K-contiguous.  24 MB traffic.
// ---------------------------------------------------------------------------
__global__ __launch_bounds__(256) void qkt_transpose_kernel(
    const float* __restrict__ qk, unsigned int* __restrict__ qkT)
{
    const int b   = blockIdx.z;
    const int m0  = blockIdx.y * 64;       // 0 or 64
    const int p0  = blockIdx.x * 64;
    const int tid = threadIdx.x;

    __shared__ unsigned int Ls[64][65];

    const float* src = qk + ((size_t)b * 128 + m0) * HW_N + p0;
    {
        const int m = tid >> 4;
        const int p = (tid & 15) * 4;
        #pragma unroll
        for (int s = 0; s < 4; ++s) {
            const float4 t = *(const float4*)(src + (size_t)(m + 16 * s) * HW_N + p);
            const float v[4] = { t.x, t.y, t.z, t.w };
            #pragma unroll
            for (int j = 0; j < 4; ++j) {
                const unsigned int hi = bf16_bits(v[j]);
                const float hif = __uint_as_float(hi << 16);
                const unsigned int lo = bf16_bits(v[j] - hif);
                Ls[m + 16 * s][p + j] = (hi << 16) | lo;
            }
        }
    }
    __syncthreads();
    unsigned int* dst = qkT + ((size_t)b * HW_N + p0) * 128 + m0;
    {
        const int p = tid >> 4;
        const int m = (tid & 15) * 4;
        #pragma unroll
        for (int s = 0; s < 4; ++s) {
            uint4 r;
            r.x = Ls[m + 0][p + 16 * s];
            r.y = Ls[m + 1][p + 16 * s];
            r.z = Ls[m + 2][p + 16 * s];
            r.w = Ls[m + 3][p + 16 * s];
            *(uint4*)(dst + (size_t)(p + 16 * s) * 128 + m) = r;
        }
    }
}

// ---------------------------------------------------------------------------
// Kernel 2 (REWRITTEN): energy[b,i,j] = sum_c q[b,c,i]*k[b,c,j] via bf16 MFMA
// with 3-product split (fp32-grade: qhi*khi + qhi*klo + qlo*khi).
// 128x128 tile, K=64 staged ONCE (no K loop), XOR-swizzled LDS.
// A rows = i (qkT cols 0..63), B rows = j (qkT cols 64..127).
// ---------------------------------------------------------------------------
__global__ __launch_bounds__(256) void energy_mfma_kernel(
    const unsigned int* __restrict__ qkT, float* __restrict__ att)
{
    const int b   = blockIdx.z;
    const int i0  = blockIdx.y * 128;
    const int j0  = blockIdx.x * 128;
    const int tid = threadIdx.x;

    __shared__ __align__(16) unsigned short AsHi[128 * 64];
    __shared__ __align__(16) unsigned short AsLo[128 * 64];
    __shared__ __align__(16) unsigned short BsHi[128 * 64];
    __shared__ __align__(16) unsigned short BsLo[128 * 64];

    const int sq = tid & 7;
    const int sr = tid >> 3;

    const int lane = tid & 63;
    const int wave = tid >> 6;
    const int wrow = (wave >> 1) * 64;    // i offset within tile
    const int wcol = (wave & 1) * 64;     // j offset within tile
    const int lrow = lane & 15;
    const int lk   = lane >> 4;

    // stage both tiles (single K slab of 64 channels)
    #pragma unroll
    for (int s = 0; s < 4; ++s) {
        const int r  = sr + 32 * s;
        const int ch = sq ^ (r & 7);
        {   // A: q channels of row i0+r
            const unsigned int* pa = qkT + ((size_t)b * HW_N + i0 + r) * 128 + sq * 8;
            const uint4 u0 = *(const uint4*)(pa);
            const uint4 u1 = *(const uint4*)(pa + 4);
            uint4 h, l;
            h.x = (u0.x >> 16) | (u0.y & 0xffff0000u);
            h.y = (u0.z >> 16) | (u0.w & 0xffff0000u);
            h.z = (u1.x >> 16) | (u1.y & 0xffff0000u);
            h.w = (u1.z >> 16) | (u1.w & 0xffff0000u);
            l.x = (u0.x & 0xffffu) | (u0.y << 16);
            l.y = (u0.z & 0xffffu) | (u0.w << 16);
            l.z = (u1.x & 0xffffu) | (u1.y << 16);
            l.w = (u1.z & 0xffffu) | (u1.w << 16);
            *reinterpret_cast<uint4*>(&AsHi[r * 64 + ch * 8]) = h;
            *reinterpret_cast<uint4*>(&AsLo[r * 64 + ch * 8]) = l;
        }
        {   // B: k channels of row j0+r
            const unsigned int* pb = qkT + ((size_t)b * HW_N + j0 + r) * 128 + 64 + sq * 8;
            const uint4 u0 = *(const uint4*)(pb);
            const uint4 u1 = *(const uint4*)(pb + 4);
            uint4 h, l;
            h.x = (u0.x >> 16) | (u0.y & 0xffff0000u);
            h.y = (u0.z >> 16) | (u0.w & 0xffff0000u);
            h.z = (u1.x >> 16) | (u1.y & 0xffff0000u);
            h.w = (u1.z >> 16) | (u1.w & 0xffff0000u);
            l.x = (u0.x & 0xffffu) | (u0.y << 16);
            l.y = (u0.z & 0xffffu) | (u0.w << 16);
            l.z = (u1.x & 0xffffu) | (u1.y << 16);
            l.w = (u1.z & 0xffffu) | (u1.w << 16);
            *reinterpret_cast<uint4*>(&BsHi[r * 64 + ch * 8]) = h;
            *reinterpret_cast<uint4*>(&BsLo[r * 64 + ch * 8]) = l;
        }
    }
    __syncthreads();

    f32x4 acc[4][4] = {};
    #pragma unroll
    for (int kb = 0; kb < 2; ++kb) {
        bf16x8 bfh[4], bfl[4];
        #pragma unroll
        for (int n = 0; n < 4; ++n) {
            const int r  = wcol + n * 16 + lrow;
            const int ch = (kb * 4 + lk) ^ (lrow & 7);
            bfh[n] = *reinterpret_cast<const bf16x8*>(&BsHi[r * 64 + ch * 8]);
            bfl[n] = *reinterpret_cast<const bf16x8*>(&BsLo[r * 64 + ch * 8]);
        }
        #pragma unroll
        for (int m = 0; m < 4; ++m) {
            const int r  = wrow + m * 16 + lrow;
            const int ch = (kb * 4 + lk) ^ (lrow & 7);
            const bf16x8 ah = *reinterpret_cast<const bf16x8*>(&AsHi[r * 64 + ch * 8]);
            const bf16x8 al = *reinterpret_cast<const bf16x8*>(&AsLo[r * 64 + ch * 8]);
            #pragma unroll
            for (int n = 0; n < 4; ++n) {
                acc[m][n] = __builtin_amdgcn_mfma_f32_16x16x32_bf16(ah, bfh[n], acc[m][n], 0, 0, 0);
                acc[m][n] = __builtin_amdgcn_mfma_f32_16x16x32_bf16(ah, bfl[n], acc[m][n], 0, 0, 0);
                acc[m][n] = __builtin_amdgcn_mfma_f32_16x16x32_bf16(al, bfh[n], acc[m][n], 0, 0, 0);
            }
        }
    }

    // epilogue: D row = i (lk*4+reg within 16-block), col = j (lrow)
    #pragma unroll
    for (int m = 0; m < 4; ++m) {
        #pragma unroll
        for (int rr = 0; rr < 4; ++rr) {
            const int i = i0 + wrow + m * 16 + lk * 4 + rr;
            float* dst = att + ((size_t)b * HW_N + i) * HW_N + j0 + wcol + lrow;
            #pragma unroll
            for (int n = 0; n < 4; ++n)
                dst[n * 16] = acc[m][n][rr];
        }
    }
}

// ---------------------------------------------------------------------------
// Kernel 3: row softmax in place (unchanged).
// ---------------------------------------------------------------------------
__global__ __launch_bounds__(256) void softmax_kernel(float* __restrict__ att)
{
    const size_t row = blockIdx.x;
    float* e = att + row * (size_t)HW_N;
    const int tid  = threadIdx.x;
    const int wv_  = tid >> 6;
    const int lane = tid & 63;

    float4 v = ((const float4*)e)[tid];

    float m = fmaxf(fmaxf(v.x, v.y), fmaxf(v.z, v.w));
    #pragma unroll
    for (int off = 32; off > 0; off >>= 1)
        m = fmaxf(m, __shfl_down(m, off, 64));
    __shared__ float red[4];
    if (lane == 0) red[wv_] = m;
    __syncthreads();
    m = fmaxf(fmaxf(red[0], red[1]), fmaxf(red[2], red[3]));
    __syncthreads();

    float4 ex;
    ex.x = __expf(v.x - m); ex.y = __expf(v.y - m);
    ex.z = __expf(v.z - m); ex.w = __expf(v.w - m);
    float s = ex.x + ex.y + ex.z + ex.w;
    #pragma unroll
    for (int off = 32; off > 0; off >>= 1)
        s += __shfl_down(s, off, 64);
    if (lane == 0) red[wv_] = s;
    __syncthreads();
    s = red[0] + red[1] + red[2] + red[3];

    const float inv = 1.0f / s;
    ex.x *= inv; ex.y *= inv; ex.z *= inv; ex.w *= inv;
    ((float4*)e)[tid] = ex;
}

// ---------------------------------------------------------------------------
// Kernel 4: out[b,c,i] = sum_j v[b,c,j] * att[b,i,j] via bf16 MFMA (unchanged).
// ---------------------------------------------------------------------------
__global__ __launch_bounds__(256) void out_kernel(
    const unsigned short* __restrict__ vout, const float* __restrict__ att,
    const float* __restrict__ x, const float* __restrict__ hha,
    const float* __restrict__ gamma,
    float* __restrict__ rgb, float* __restrict__ hho)
{
    const int b   = blockIdx.z;
    const int c0  = blockIdx.y * 128;
    const int i0  = blockIdx.x * 128;
    const int tid = threadIdx.x;

    const unsigned short* vptr = vout + (size_t)(b * C_N + c0) * HW_N;
    const float* aptr = att + (size_t)b * HW_N * HW_N + (size_t)i0 * HW_N;

    __shared__ __align__(16) unsigned short Vs[128 * 64];
    __shared__ __align__(16) unsigned short Ps[128 * 64];

    const int sq = tid & 7;
    const int sr = tid >> 3;

    const int lane = tid & 63;
    const int wave = tid >> 6;
    const int wrow = (wave >> 1) * 64;
    const int wcol = (wave & 1) * 64;
    const int lrow = lane & 15;
    const int lk   = lane >> 4;

    f32x4 acc[4][4] = {};
    uint4  ra[4];
    float4 rb[4][2];

    auto load_tiles = [&](int j0) {
        #pragma unroll
        for (int s = 0; s < 4; ++s) {
            ra[s] = *(const uint4*)(vptr + (size_t)(sr + 32 * s) * HW_N + j0 + sq * 8);
            const float* pb = aptr + (size_t)(sr + 32 * s) * HW_N + j0 + sq * 8;
            rb[s][0] = *(const float4*)(pb);
            rb[s][1] = *(const float4*)(pb + 4);
        }
    };

    auto write_tiles = [&]() {
        #pragma unroll
        for (int s = 0; s < 4; ++s) {
            const int r  = sr + 32 * s;
            const int ch = sq ^ (r & 7);
            *reinterpret_cast<uint4*>(&Vs[r * 64 + ch * 8]) = ra[s];
            uint4 wb;
            wb.x = pack2_bf16(rb[s][0].x, rb[s][0].y);
            wb.y = pack2_bf16(rb[s][0].z, rb[s][0].w);
            wb.z = pack2_bf16(rb[s][1].x, rb[s][1].y);
            wb.w = pack2_bf16(rb[s][1].z, rb[s][1].w);
            *reinterpret_cast<uint4*>(&Ps[r * 64 + ch * 8]) = wb;
        }
    };

    load_tiles(0);
    for (int jt = 0; jt < HW_N / 64; ++jt) {
        __syncthreads();
        write_tiles();
        __syncthreads();
        if (jt + 1 < HW_N / 64) load_tiles((jt + 1) * 64);

        #pragma unroll
        for (int kb = 0; kb < 2; ++kb) {
            bf16x8 af[4], bf[4];
            #pragma unroll
            for (int m = 0; m < 4; ++m) {
                const int r  = wrow + m * 16 + lrow;
                const int ch = (kb * 4 + lk) ^ (lrow & 7);
                af[m] = *reinterpret_cast<const bf16x8*>(&Vs[r * 64 + ch * 8]);
            }
            #pragma unroll
            for (int n = 0; n < 4; ++n) {
                const int r  = wcol + n * 16 + lrow;
                const int ch = (kb * 4 + lk) ^ (lrow & 7);
                bf[n] = *reinterpret_cast<const bf16x8*>(&Ps[r * 64 + ch * 8]);
            }
            #pragma unroll
            for (int m = 0; m < 4; ++m)
                #pragma unroll
                for (int n = 0; n < 4; ++n)
                    acc[m][n] = __builtin_amdgcn_mfma_f32_16x16x32_bf16(
                        af[m], bf[n], acc[m][n], 0, 0, 0);
        }
    }

    const float g    = gamma[0];
    const int   crow = c0 + wrow + lk * 4;
    const int   icol = i0 + wcol + lrow;
    #pragma unroll
    for (int m = 0; m < 4; ++m) {
        #pragma unroll
        for (int rr = 0; rr < 4; ++rr) {
            const int c = crow + m * 16 + rr;
            const size_t base = ((size_t)b * C_N + c) * HW_N + icol;
            #pragma unroll
            for (int n = 0; n < 4; ++n) {
                const float o  = acc[m][n][rr];
                const float xv = x[base + n * 16];
                const float hv = hha[base + n * 16];
                rgb[base + n * 16] = fmaf(g, o, xv);
                hho[base + n * 16] = fmaf(g, o, hv);
            }
        }
    }
}

// ---------------------------------------------------------------------------
extern "C" void kernel_launch(void* const* d_in, const int* in_sizes, int n_in,
                              void* d_out, int out_size, void* d_ws, size_t ws_size,
                              hipStream_t stream)
{
    const float* x     = (const float*)d_in[0];
    const float* hha   = (const float*)d_in[1];
    const float* wq    = (const float*)d_in[2];
    const float* bq    = (const float*)d_in[3];
    const float* wk    = (const float*)d_in[4];
    const float* bk    = (const float*)d_in[5];
    const float* wv    = (const float*)d_in[6];
    const float* bv    = (const float*)d_in[7];
    const float* gamma = (const float*)d_in[8];

    float* out = (float*)d_out;
    float* att = out;                                        // [32,1024,1024]
    float* rgb = att + (size_t)B_N * HW_N * HW_N;            // [32,512,1024]
    float* hho = rgb + (size_t)B_N * C_N * HW_N;             // [32,512,1024]

    // workspace layout:
    //   qkbuf  fp32 [32][128][1024]  = 16 MiB
    //   vbuf   bf16 [32][512][1024]  = 32 MiB
    //   qkT    u32  [32][1024][128]  = 16 MiB
    float*          qkbuf = (float*)d_ws;
    unsigned short* vbuf  = (unsigned short*)(qkbuf + (size_t)B_N * 128 * HW_N);
    unsigned int*   qkTb  = (unsigned int*)(vbuf + (size_t)B_N * C_N * HW_N);

    // xT split lives in the (not yet written) att region: 64 MiB of 128 MiB
    unsigned int* xt = (unsigned int*)att;

    xsplit_transpose_kernel<<<dim3(HW_N / 64, C_N / 64, B_N), 256, 0, stream>>>(x, xt);
    qkv_mfma_kernel<<<dim3(HW_N / 128, 5, B_N), 256, 0, stream>>>(
        xt, wq, bq, wk, bk, wv, bv, qkbuf, vbuf);
    qkt_transpose_kernel<<<dim3(HW_N / 64, 2, B_N), 256, 0, stream>>>(qkbuf, qkTb);
    energy_mfma_kernel<<<dim3(HW_N / 128, HW_N / 128, B_N), 256, 0, stream>>>(qkTb, att);
    softmax_kernel<<<dim3(B_N * HW_N), 256, 0, stream>>>(att);
    out_kernel<<<dim3(HW_N / 128, C_N / 128, B_N), 256, 0, stream>>>(
        vbuf, att, x, hha, gamma, rgb, hho);
}